// Round 1
// baseline (259.385 us; speedup 1.0000x reference)
//
#include <hip/hip_runtime.h>

#define TPB   256            // threads per block
#define CELLS 256            // cells per block (== TPB, 1 cell/thread)
#define FPC   30             // floats per cell (5*B + C = 30)
#define PAD   31             // padded LDS stride (gcd(31,32)=1 -> conflict-free)
#define TILE_F   (CELLS * FPC)   // 7680 floats per input per tile
#define TILE_F4  (TILE_F / 4)    // 1920 float4 per input per tile

__launch_bounds__(TPB)
__global__ void yolo_loss_kernel(const float* __restrict__ bb,
                                 const float* __restrict__ gt,
                                 float* __restrict__ out,
                                 int ncells) {
    __shared__ float sBB[CELLS * PAD];
    __shared__ float sGT[CELLS * PAD];
    __shared__ float sRed[TPB / 64][6];

    const int tid = threadIdx.x;
    const int bid = blockIdx.x;

    // ---- Stage tile: coalesced float4 global loads -> padded LDS ----------
    const int tileBaseF4 = bid * TILE_F4;              // float4 index of tile start
    const int totalF4    = (ncells * FPC) >> 2;        // total float4 in each input
    const float4* __restrict__ bb4 = (const float4*)bb;
    const float4* __restrict__ gt4 = (const float4*)gt;

    for (int idx = tid; idx < TILE_F4; idx += TPB) {
        int f4i = tileBaseF4 + idx;
        if (f4i < totalF4) {
            float4 vb = bb4[f4i];
            float4 vg = gt4[f4i];
            unsigned e = (unsigned)idx * 4u;           // float offset within tile
#pragma unroll
            for (int j = 0; j < 4; ++j) {
                unsigned ee = e + (unsigned)j;
                unsigned a  = ee + ee / 30u;           // cell*31 + k
                sBB[a] = ((const float*)&vb)[j];
                sGT[a] = ((const float*)&vg)[j];
            }
        }
    }
    __syncthreads();

    // ---- Per-cell compute --------------------------------------------------
    float L = 0.f, Lc = 0.f, Lconf = 0.f, Lcls = 0.f, Isum = 0.f, On = 0.f;
    const int cell = bid * CELLS + tid;
    if (cell < ncells) {
        const float* __restrict__ Bp = &sBB[tid * PAD];
        const float* __restrict__ Gp = &sGT[tid * PAD];

        const int w = cell % 49;                 // cell within image (S*S = 49)
        const float gx = (float)(w % 7) * 64.0f; // col * GRID
        const float gy = (float)(w / 7) * 64.0f; // row * GRID

        const float g0 = Gp[5], g1 = Gp[6], g2 = Gp[7], g3 = Gp[8];
        const float g_area = (g2 - g0) * (g3 - g1);

        const float b1x = Bp[0], b1y = Bp[1], b1w = Bp[2], b1h = Bp[3], b1c = Bp[4];
        const float b2x = Bp[5], b2y = Bp[6], b2w = Bp[7], b2h = Bp[8], b2c = Bp[9];

        auto iou_of = [&](float bx, float by, float bw, float bh) -> float {
            float px = truncf(gx + bx * 64.0f);
            float py = truncf(gy + by * 64.0f);
            float pw = truncf(bw * 448.0f);
            float ph = truncf(bh * 448.0f);
            float x1 = fmaxf(0.0f,   px - pw * 0.5f);
            float y1 = fmaxf(0.0f,   py - ph * 0.5f);
            float x2 = fminf(447.0f, px + pw * 0.5f);
            float y2 = fminf(447.0f, py + ph * 0.5f);
            float parea = (x2 - x1) * (y2 - y1);
            float lx = fmaxf(x1, g0), rx = fminf(x2, g2);
            float uy = fmaxf(y1, g1), dn = fminf(y2, g3);
            float inter = (rx - lx) * (dn - uy);
            float denom = parea + g_area - inter;
            denom = (denom == 0.0f) ? 1.0f : denom;
            return ((rx >= lx) && (dn >= uy)) ? (inter / denom) : 0.0f;
        };

        const float iou1 = iou_of(b1x, b1y, b1w, b1h);
        const float iou2 = iou_of(b2x, b2y, b2w, b2h);
        const bool  p1   = iou1 > iou2;

        const float pbx = p1 ? b1x : b2x, pby = p1 ? b1y : b2y;
        const float pbw = p1 ? b1w : b2w, pbh = p1 ? b1h : b2h;
        const float pbc = p1 ? b1c : b2c;
        const float npc = p1 ? b2c : b1c;
        const float iousel = p1 ? iou1 : iou2;

        const bool obj = (rintf(Gp[9]) != 0.0f);     // jnp.round: half-to-even

        const float dx = Gp[0] - pbx;
        const float dy = Gp[1] - pby;
        const float dw = sqrtf(Gp[2] + 1e-8f) - sqrtf(pbw + 1e-8f);
        const float dh = sqrtf(Gp[3] + 1e-8f) - sqrtf(pbh + 1e-8f);
        const float coord = 5.0f * (dx * dx + dy * dy + dw * dw + dh * dh);

        float confobj = pbc - iousel;
        confobj *= confobj;

        float cls = 0.f;
#pragma unroll
        for (int k = 0; k < 20; ++k) {
            float d = Gp[10 + k] - Bp[10 + k];
            cls += d * d;
        }
        cls *= (1.0f / 20.0f);

        const float noobj_of_obj = 0.5f * npc * npc;
        const float objloss   = coord + confobj + cls + noobj_of_obj;
        const float noobjloss = 0.5f * b1c * b1c + b2c * b2c;   // asymmetric, per reference

        if (obj) {
            L = objloss; Lc = coord; Lconf = confobj + npc * npc;
            Lcls = cls;  Isum = iousel; On = 1.0f;
        } else {
            L = noobjloss; Lconf = noobjloss;
        }
    }

    // ---- Reduction: wave shuffle -> LDS -> block atomics -------------------
    float v[6] = {L, Lc, Lconf, Lcls, Isum, On};
#pragma unroll
    for (int k = 0; k < 6; ++k) {
#pragma unroll
        for (int off = 32; off > 0; off >>= 1)
            v[k] += __shfl_down(v[k], off, 64);
    }
    const int wave = tid >> 6;
    const int lane = tid & 63;
    if (lane == 0) {
#pragma unroll
        for (int k = 0; k < 6; ++k) sRed[wave][k] = v[k];
    }
    __syncthreads();
    if (tid == 0) {
#pragma unroll
        for (int k = 0; k < 6; ++k) {
            float s = sRed[0][k] + sRed[1][k] + sRed[2][k] + sRed[3][k];
            atomicAdd(&out[k], s);
        }
    }
}

extern "C" void kernel_launch(void* const* d_in, const int* in_sizes, int n_in,
                              void* d_out, int out_size, void* d_ws, size_t ws_size,
                              hipStream_t stream) {
    const float* bb = (const float*)d_in[0];
    const float* gt = (const float*)d_in[1];
    float* out = (float*)d_out;

    const int ncells = in_sizes[0] / FPC;            // N*S*S = 802816
    const int grid   = (ncells + CELLS - 1) / CELLS; // 3136

    hipMemsetAsync(d_out, 0, (size_t)out_size * sizeof(float), stream);
    yolo_loss_kernel<<<grid, TPB, 0, stream>>>(bb, gt, out, ncells);
}

// Round 2
// 48.788 us; speedup vs baseline: 5.3165x; 5.3165x over previous
//
#include <hip/hip_runtime.h>

#define TPB   256            // threads per block
#define CELLS 256            // cells per block (== TPB, 1 cell/thread)
#define FPC   30             // floats per cell (5*B + C = 30)
#define PAD   31             // padded LDS stride (gcd(31,32)=1 -> conflict-free)
#define TILE_F   (CELLS * FPC)   // 7680 floats per input per tile
#define TILE_F4  (TILE_F / 4)    // 1920 float4 per input per tile

__launch_bounds__(TPB)
__global__ void yolo_loss_kernel(const float* __restrict__ bb,
                                 const float* __restrict__ gt,
                                 float* __restrict__ ws,
                                 int ncells, int nblocks) {
    __shared__ float sBB[CELLS * PAD];
    __shared__ float sGT[CELLS * PAD];
    __shared__ float sRed[TPB / 64][6];

    const int tid = threadIdx.x;
    const int bid = blockIdx.x;

    // ---- Stage tile: coalesced float4 global loads -> padded LDS ----------
    const int tileBaseF4 = bid * TILE_F4;              // float4 index of tile start
    const int totalF4    = (ncells * FPC) >> 2;        // total float4 in each input
    const float4* __restrict__ bb4 = (const float4*)bb;
    const float4* __restrict__ gt4 = (const float4*)gt;

    for (int idx = tid; idx < TILE_F4; idx += TPB) {
        int f4i = tileBaseF4 + idx;
        if (f4i < totalF4) {
            float4 vb = bb4[f4i];
            float4 vg = gt4[f4i];
            unsigned e = (unsigned)idx * 4u;           // float offset within tile
#pragma unroll
            for (int j = 0; j < 4; ++j) {
                unsigned ee = e + (unsigned)j;
                unsigned a  = ee + ee / 30u;           // cell*31 + k
                sBB[a] = ((const float*)&vb)[j];
                sGT[a] = ((const float*)&vg)[j];
            }
        }
    }
    __syncthreads();

    // ---- Per-cell compute --------------------------------------------------
    float L = 0.f, Lc = 0.f, Lconf = 0.f, Lcls = 0.f, Isum = 0.f, On = 0.f;
    const int cell = bid * CELLS + tid;
    if (cell < ncells) {
        const float* __restrict__ Bp = &sBB[tid * PAD];
        const float* __restrict__ Gp = &sGT[tid * PAD];

        const int w = cell % 49;                 // cell within image (S*S = 49)
        const float gx = (float)(w % 7) * 64.0f; // col * GRID
        const float gy = (float)(w / 7) * 64.0f; // row * GRID

        const float g0 = Gp[5], g1 = Gp[6], g2 = Gp[7], g3 = Gp[8];
        const float g_area = (g2 - g0) * (g3 - g1);

        const float b1x = Bp[0], b1y = Bp[1], b1w = Bp[2], b1h = Bp[3], b1c = Bp[4];
        const float b2x = Bp[5], b2y = Bp[6], b2w = Bp[7], b2h = Bp[8], b2c = Bp[9];

        auto iou_of = [&](float bx, float by, float bw, float bh) -> float {
            float px = truncf(gx + bx * 64.0f);
            float py = truncf(gy + by * 64.0f);
            float pw = truncf(bw * 448.0f);
            float ph = truncf(bh * 448.0f);
            float x1 = fmaxf(0.0f,   px - pw * 0.5f);
            float y1 = fmaxf(0.0f,   py - ph * 0.5f);
            float x2 = fminf(447.0f, px + pw * 0.5f);
            float y2 = fminf(447.0f, py + ph * 0.5f);
            float parea = (x2 - x1) * (y2 - y1);
            float lx = fmaxf(x1, g0), rx = fminf(x2, g2);
            float uy = fmaxf(y1, g1), dn = fminf(y2, g3);
            float inter = (rx - lx) * (dn - uy);
            float denom = parea + g_area - inter;
            denom = (denom == 0.0f) ? 1.0f : denom;
            return ((rx >= lx) && (dn >= uy)) ? (inter / denom) : 0.0f;
        };

        const float iou1 = iou_of(b1x, b1y, b1w, b1h);
        const float iou2 = iou_of(b2x, b2y, b2w, b2h);
        const bool  p1   = iou1 > iou2;

        const float pbx = p1 ? b1x : b2x, pby = p1 ? b1y : b2y;
        const float pbw = p1 ? b1w : b2w, pbh = p1 ? b1h : b2h;
        const float pbc = p1 ? b1c : b2c;
        const float npc = p1 ? b2c : b1c;
        const float iousel = p1 ? iou1 : iou2;

        const bool obj = (rintf(Gp[9]) != 0.0f);     // jnp.round: half-to-even

        const float dx = Gp[0] - pbx;
        const float dy = Gp[1] - pby;
        const float dw = sqrtf(Gp[2] + 1e-8f) - sqrtf(pbw + 1e-8f);
        const float dh = sqrtf(Gp[3] + 1e-8f) - sqrtf(pbh + 1e-8f);
        const float coord = 5.0f * (dx * dx + dy * dy + dw * dw + dh * dh);

        float confobj = pbc - iousel;
        confobj *= confobj;

        float cls = 0.f;
#pragma unroll
        for (int k = 0; k < 20; ++k) {
            float d = Gp[10 + k] - Bp[10 + k];
            cls += d * d;
        }
        cls *= (1.0f / 20.0f);

        const float noobj_of_obj = 0.5f * npc * npc;
        const float objloss   = coord + confobj + cls + noobj_of_obj;
        const float noobjloss = 0.5f * b1c * b1c + b2c * b2c;   // asymmetric, per reference

        if (obj) {
            L = objloss; Lc = coord; Lconf = confobj + npc * npc;
            Lcls = cls;  Isum = iousel; On = 1.0f;
        } else {
            L = noobjloss; Lconf = noobjloss;
        }
    }

    // ---- Reduction: wave shuffle -> LDS -> ONE partial store per block -----
    float v[6] = {L, Lc, Lconf, Lcls, Isum, On};
#pragma unroll
    for (int k = 0; k < 6; ++k) {
#pragma unroll
        for (int off = 32; off > 0; off >>= 1)
            v[k] += __shfl_down(v[k], off, 64);
    }
    const int wave = tid >> 6;
    const int lane = tid & 63;
    if (lane == 0) {
#pragma unroll
        for (int k = 0; k < 6; ++k) sRed[wave][k] = v[k];
    }
    __syncthreads();
    if (tid == 0) {
#pragma unroll
        for (int k = 0; k < 6; ++k) {
            float s = sRed[0][k] + sRed[1][k] + sRed[2][k] + sRed[3][k];
            ws[k * nblocks + bid] = s;          // plain store, no atomics
        }
    }
}

// Second stage: 6 blocks, one per output scalar; each reduces nblocks partials.
__global__ void reduce_partials(const float* __restrict__ ws,
                                float* __restrict__ out, int nblocks) {
    __shared__ float sw[4];
    const int k = blockIdx.x;
    float s = 0.f;
    for (int i = threadIdx.x; i < nblocks; i += blockDim.x)
        s += ws[k * nblocks + i];
#pragma unroll
    for (int off = 32; off > 0; off >>= 1)
        s += __shfl_down(s, off, 64);
    if ((threadIdx.x & 63) == 0) sw[threadIdx.x >> 6] = s;
    __syncthreads();
    if (threadIdx.x == 0) out[k] = sw[0] + sw[1] + sw[2] + sw[3];
}

extern "C" void kernel_launch(void* const* d_in, const int* in_sizes, int n_in,
                              void* d_out, int out_size, void* d_ws, size_t ws_size,
                              hipStream_t stream) {
    const float* bb = (const float*)d_in[0];
    const float* gt = (const float*)d_in[1];
    float* out = (float*)d_out;
    float* ws  = (float*)d_ws;

    const int ncells = in_sizes[0] / FPC;            // N*S*S = 802816
    const int grid   = (ncells + CELLS - 1) / CELLS; // 3136

    yolo_loss_kernel<<<grid, TPB, 0, stream>>>(bb, gt, ws, ncells, grid);
    reduce_partials<<<6, 256, 0, stream>>>(ws, out, grid);
}

// Round 3
// 38.299 us; speedup vs baseline: 6.7726x; 1.2739x over previous
//
#include <hip/hip_runtime.h>

#define TPB   256            // threads per block
#define CELLS 256            // cells per block (== TPB, 1 cell/thread)
#define FPC   30             // floats per cell (5*B + C = 30)
#define PAD   31             // padded LDS stride (gcd(31,32)=1 -> conflict-free)
#define TILE_F   (CELLS * FPC)   // 7680 floats per input per tile
#define TILE_F4  (TILE_F / 4)    // 1920 float4 per input per tile
#define ITERS    8               // ceil(1920 / 256); last iter covers 128 threads
#define TAIL     (TILE_F4 - (ITERS - 1) * TPB)   // 128

__launch_bounds__(TPB)
__global__ void yolo_loss_kernel(const float* __restrict__ bb,
                                 const float* __restrict__ gt,
                                 float* __restrict__ ws,
                                 int ncells, int nblocks) {
    __shared__ float sBB[CELLS * PAD];
    __shared__ float sGT[CELLS * PAD];
    __shared__ float sRed[TPB / 64][6];

    const int tid = threadIdx.x;
    const int bid = blockIdx.x;

    // ---- Stage tile: ALL loads issued first (16 float4 in flight/thread),
    // ---- then drain into padded LDS. Grid arithmetic is exact, so the only
    // ---- guard is the in-tile tail on the last iteration.
    const float4* __restrict__ src_b = (const float4*)bb + (size_t)bid * TILE_F4;
    const float4* __restrict__ src_g = (const float4*)gt + (size_t)bid * TILE_F4;

    float4 rb[ITERS], rg[ITERS];
#pragma unroll
    for (int i = 0; i < ITERS; ++i) {
        const int idx = i * TPB + tid;
        if (i < ITERS - 1 || tid < TAIL) {
            rb[i] = src_b[idx];
            rg[i] = src_g[idx];
        }
    }
#pragma unroll
    for (int i = 0; i < ITERS; ++i) {
        const int idx = i * TPB + tid;
        if (i < ITERS - 1 || tid < TAIL) {
            const unsigned e = (unsigned)idx * 4u;   // float offset within tile
#pragma unroll
            for (int j = 0; j < 4; ++j) {
                const unsigned ee = e + (unsigned)j;
                const unsigned a  = ee + ee / 30u;   // cell*31 + k (PAD=31)
                sBB[a] = ((const float*)&rb[i])[j];
                sGT[a] = ((const float*)&rg[i])[j];
            }
        }
    }
    __syncthreads();

    // ---- Per-cell compute --------------------------------------------------
    float L = 0.f, Lc = 0.f, Lconf = 0.f, Lcls = 0.f, Isum = 0.f, On = 0.f;
    const int cell = bid * CELLS + tid;
    if (cell < ncells) {
        const float* __restrict__ Bp = &sBB[tid * PAD];
        const float* __restrict__ Gp = &sGT[tid * PAD];

        const int w = cell % 49;                 // cell within image (S*S = 49)
        const float gx = (float)(w % 7) * 64.0f; // col * GRID
        const float gy = (float)(w / 7) * 64.0f; // row * GRID

        const float g0 = Gp[5], g1 = Gp[6], g2 = Gp[7], g3 = Gp[8];
        const float g_area = (g2 - g0) * (g3 - g1);

        const float b1x = Bp[0], b1y = Bp[1], b1w = Bp[2], b1h = Bp[3], b1c = Bp[4];
        const float b2x = Bp[5], b2y = Bp[6], b2w = Bp[7], b2h = Bp[8], b2c = Bp[9];

        auto iou_of = [&](float bx, float by, float bw, float bh) -> float {
            float px = truncf(gx + bx * 64.0f);
            float py = truncf(gy + by * 64.0f);
            float pw = truncf(bw * 448.0f);
            float ph = truncf(bh * 448.0f);
            float x1 = fmaxf(0.0f,   px - pw * 0.5f);
            float y1 = fmaxf(0.0f,   py - ph * 0.5f);
            float x2 = fminf(447.0f, px + pw * 0.5f);
            float y2 = fminf(447.0f, py + ph * 0.5f);
            float parea = (x2 - x1) * (y2 - y1);
            float lx = fmaxf(x1, g0), rx = fminf(x2, g2);
            float uy = fmaxf(y1, g1), dn = fminf(y2, g3);
            float inter = (rx - lx) * (dn - uy);
            float denom = parea + g_area - inter;
            denom = (denom == 0.0f) ? 1.0f : denom;
            return ((rx >= lx) && (dn >= uy)) ? (inter / denom) : 0.0f;
        };

        const float iou1 = iou_of(b1x, b1y, b1w, b1h);
        const float iou2 = iou_of(b2x, b2y, b2w, b2h);
        const bool  p1   = iou1 > iou2;

        const float pbx = p1 ? b1x : b2x, pby = p1 ? b1y : b2y;
        const float pbw = p1 ? b1w : b2w, pbh = p1 ? b1h : b2h;
        const float pbc = p1 ? b1c : b2c;
        const float npc = p1 ? b2c : b1c;
        const float iousel = p1 ? iou1 : iou2;

        const bool obj = (rintf(Gp[9]) != 0.0f);     // jnp.round: half-to-even

        const float dx = Gp[0] - pbx;
        const float dy = Gp[1] - pby;
        const float dw = sqrtf(Gp[2] + 1e-8f) - sqrtf(pbw + 1e-8f);
        const float dh = sqrtf(Gp[3] + 1e-8f) - sqrtf(pbh + 1e-8f);
        const float coord = 5.0f * (dx * dx + dy * dy + dw * dw + dh * dh);

        float confobj = pbc - iousel;
        confobj *= confobj;

        float cls = 0.f;
#pragma unroll
        for (int k = 0; k < 20; ++k) {
            float d = Gp[10 + k] - Bp[10 + k];
            cls += d * d;
        }
        cls *= (1.0f / 20.0f);

        const float noobj_of_obj = 0.5f * npc * npc;
        const float objloss   = coord + confobj + cls + noobj_of_obj;
        const float noobjloss = 0.5f * b1c * b1c + b2c * b2c;   // asymmetric, per reference

        if (obj) {
            L = objloss; Lc = coord; Lconf = confobj + npc * npc;
            Lcls = cls;  Isum = iousel; On = 1.0f;
        } else {
            L = noobjloss; Lconf = noobjloss;
        }
    }

    // ---- Reduction: wave shuffle -> LDS -> ONE partial store per block -----
    float v[6] = {L, Lc, Lconf, Lcls, Isum, On};
#pragma unroll
    for (int k = 0; k < 6; ++k) {
#pragma unroll
        for (int off = 32; off > 0; off >>= 1)
            v[k] += __shfl_down(v[k], off, 64);
    }
    const int wave = tid >> 6;
    const int lane = tid & 63;
    if (lane == 0) {
#pragma unroll
        for (int k = 0; k < 6; ++k) sRed[wave][k] = v[k];
    }
    __syncthreads();
    if (tid == 0) {
#pragma unroll
        for (int k = 0; k < 6; ++k) {
            float s = sRed[0][k] + sRed[1][k] + sRed[2][k] + sRed[3][k];
            ws[k * nblocks + bid] = s;          // plain store, no atomics
        }
    }
}

// Second stage: 6 blocks, one per output scalar; each reduces nblocks partials.
__global__ void reduce_partials(const float* __restrict__ ws,
                                float* __restrict__ out, int nblocks) {
    __shared__ float sw[4];
    const int k = blockIdx.x;
    float s = 0.f;
    for (int i = threadIdx.x; i < nblocks; i += blockDim.x)
        s += ws[k * nblocks + i];
#pragma unroll
    for (int off = 32; off > 0; off >>= 1)
        s += __shfl_down(s, off, 64);
    if ((threadIdx.x & 63) == 0) sw[threadIdx.x >> 6] = s;
    __syncthreads();
    if (threadIdx.x == 0) out[k] = sw[0] + sw[1] + sw[2] + sw[3];
}

extern "C" void kernel_launch(void* const* d_in, const int* in_sizes, int n_in,
                              void* d_out, int out_size, void* d_ws, size_t ws_size,
                              hipStream_t stream) {
    const float* bb = (const float*)d_in[0];
    const float* gt = (const float*)d_in[1];
    float* out = (float*)d_out;
    float* ws  = (float*)d_ws;

    const int ncells = in_sizes[0] / FPC;            // N*S*S = 802816
    const int grid   = (ncells + CELLS - 1) / CELLS; // 3136

    yolo_loss_kernel<<<grid, TPB, 0, stream>>>(bb, gt, ws, ncells, grid);
    reduce_partials<<<6, 256, 0, stream>>>(ws, out, grid);
}